// Round 1
// baseline (294.165 us; speedup 1.0000x reference)
//
#include <hip/hip_runtime.h>

#define N_POS 4096
#define NJ 4094   // N-2 valid sign-change positions

// ---------------------------------------------------------------------------
// Kernel 1: count peaks/valleys of the second difference.
// Grid: (4 position-chunks of 1024, 128 row-groups), block 256.
// Each thread owns 4 consecutive positions, accumulates counts over 64 rows
// in registers, then does one atomicAdd per (position, kind).
// ---------------------------------------------------------------------------
__global__ __launch_bounds__(256) void count_kernel(
    const float* __restrict__ x,
    unsigned int* __restrict__ peak,
    unsigned int* __restrict__ valley,
    int rows_per_block)
{
    const int tid  = threadIdx.x;
    const int lane = tid & 63;
    const int j0   = blockIdx.x * 1024 + tid * 4;
    const int row0 = blockIdx.y * rows_per_block;

    unsigned int pk0 = 0, pk1 = 0, pk2 = 0, pk3 = 0;
    unsigned int vl0 = 0, vl1 = 0, vl2 = 0, vl3 = 0;

    for (int r = 0; r < rows_per_block; ++r) {
        const float* rowp = x + (size_t)(row0 + r) * N_POS;
        float4 a = *reinterpret_cast<const float4*>(rowp + j0);
        // halo: x[j0+4], x[j0+5] come from lane+1's a.x/a.y
        float n0 = __shfl_down(a.x, 1);
        float n1 = __shfl_down(a.y, 1);
        if (lane == 63) {
            if (j0 + 5 < N_POS) { n0 = rowp[j0 + 4]; n1 = rowp[j0 + 5]; }
            else                { n0 = 0.f;          n1 = 0.f; }
        }
        float d1, d2, s;
        d1 = a.y - a.x; d2 = a.z - a.y; s = d2 - d1;
        pk0 += (s < 0.f); vl0 += (s > 0.f);
        d1 = a.z - a.y; d2 = a.w - a.z; s = d2 - d1;
        pk1 += (s < 0.f); vl1 += (s > 0.f);
        d1 = a.w - a.z; d2 = n0 - a.w;  s = d2 - d1;
        pk2 += (s < 0.f); vl2 += (s > 0.f);
        d1 = n0 - a.w;  d2 = n1 - n0;   s = d2 - d1;
        pk3 += (s < 0.f); vl3 += (s > 0.f);
    }

    if (j0 + 0 < NJ) { atomicAdd(&peak[j0 + 0], pk0); atomicAdd(&valley[j0 + 0], vl0); }
    if (j0 + 1 < NJ) { atomicAdd(&peak[j0 + 1], pk1); atomicAdd(&valley[j0 + 1], vl1); }
    if (j0 + 2 < NJ) { atomicAdd(&peak[j0 + 2], pk2); atomicAdd(&valley[j0 + 2], vl2); }
    if (j0 + 3 < NJ) { atomicAdd(&peak[j0 + 3], pk3); atomicAdd(&valley[j0 + 3], vl3); }
}

// ---------------------------------------------------------------------------
// Kernel 2: vec[p] = sum_j peak[j]*exp(-((p-(j+1))/wp)^2) + valley[j]*...
// Gaussian truncated at radius ceil(8w)+1 (terms < e^-64 — negligible vs
// the 2e-2 absmax threshold on a [0,1]-normalized output).
// ---------------------------------------------------------------------------
__global__ __launch_bounds__(256) void vec_kernel(
    const unsigned int* __restrict__ peak,
    const unsigned int* __restrict__ valley,
    const float* __restrict__ log_pw,
    const float* __restrict__ log_vw,
    float* __restrict__ vec)
{
    int p = blockIdx.x * blockDim.x + threadIdx.x;
    if (p >= N_POS) return;

    float wp = __expf(log_pw[0]);
    float wv = __expf(log_vw[0]);
    float inv_p2 = 1.f / (wp * wp);
    float inv_v2 = 1.f / (wv * wv);
    int Rp = min(NJ, (int)ceilf(wp * 8.f) + 1);
    int Rv = min(NJ, (int)ceilf(wv * 8.f) + 1);

    float sum = 0.f;
    {
        int jlo = max(0, p - 1 - Rp), jhi = min(NJ - 1, p - 1 + Rp);
        for (int j = jlo; j <= jhi; ++j) {
            float dist = (float)(p - (j + 1));
            sum += (float)peak[j] * __expf(-dist * dist * inv_p2);
        }
    }
    {
        int jlo = max(0, p - 1 - Rv), jhi = min(NJ - 1, p - 1 + Rv);
        for (int j = jlo; j <= jhi; ++j) {
            float dist = (float)(p - (j + 1));
            sum += (float)valley[j] * __expf(-dist * dist * inv_v2);
        }
    }
    vec[p] = sum;
}

// ---------------------------------------------------------------------------
// Kernel 3: min/max over 4096 values + normalize into nvec. One block.
// ---------------------------------------------------------------------------
__global__ __launch_bounds__(256) void norm_kernel(
    const float* __restrict__ vec, float* __restrict__ nvec)
{
    __shared__ float smin[4], smax[4];
    const int tid = threadIdx.x;

    float lmin = 1e30f, lmax = -1e30f;
    for (int i = tid; i < N_POS; i += 256) {
        float v = vec[i];
        lmin = fminf(lmin, v);
        lmax = fmaxf(lmax, v);
    }
    for (int off = 32; off; off >>= 1) {
        lmin = fminf(lmin, __shfl_down(lmin, off));
        lmax = fmaxf(lmax, __shfl_down(lmax, off));
    }
    const int wave = tid >> 6;
    if ((tid & 63) == 0) { smin[wave] = lmin; smax[wave] = lmax; }
    __syncthreads();
    if (tid == 0) {
        smin[0] = fminf(fminf(smin[0], smin[1]), fminf(smin[2], smin[3]));
        smax[0] = fmaxf(fmaxf(smax[0], smax[1]), fmaxf(smax[2], smax[3]));
    }
    __syncthreads();
    const float vmin = smin[0];
    const float inv  = 1.f / (smax[0] - vmin + 1e-6f);
    for (int i = tid; i < N_POS; i += 256)
        nvec[i] = (vec[i] - vmin) * inv;
}

// ---------------------------------------------------------------------------
// Kernel 4: broadcast nvec (16 KiB, L1/L2-resident) to all B*C rows.
// ---------------------------------------------------------------------------
__global__ __launch_bounds__(256) void bcast_kernel(
    const float4* __restrict__ nvec4, float4* __restrict__ out4, int total4)
{
    int idx    = blockIdx.x * blockDim.x + threadIdx.x;
    int stride = gridDim.x * blockDim.x;
    for (int i = idx; i < total4; i += stride)
        out4[i] = nvec4[i & 1023];   // N/4 = 1024 (power of two)
}

extern "C" void kernel_launch(void* const* d_in, const int* in_sizes, int n_in,
                              void* d_out, int out_size, void* d_ws, size_t ws_size,
                              hipStream_t stream) {
    const float* x   = (const float*)d_in[0];
    const float* lpw = (const float*)d_in[1];
    const float* lvw = (const float*)d_in[2];
    float* out = (float*)d_out;

    unsigned int* peak   = (unsigned int*)d_ws;
    unsigned int* valley = peak + 4096;
    float* vec  = (float*)(valley + 4096);
    float* nvec = vec + 4096;

    const int rows = in_sizes[0] / N_POS;          // 8192
    const int row_groups = 128;
    const int rows_per_block = rows / row_groups;  // 64

    // zero the counters (ws is poisoned 0xAA before every timed launch)
    hipMemsetAsync(d_ws, 0, 2 * 4096 * sizeof(unsigned int), stream);

    dim3 g1(4, row_groups);
    count_kernel<<<g1, 256, 0, stream>>>(x, peak, valley, rows_per_block);
    vec_kernel<<<N_POS / 256, 256, 0, stream>>>(peak, valley, lpw, lvw, vec);
    norm_kernel<<<1, 256, 0, stream>>>(vec, nvec);
    bcast_kernel<<<2048, 256, 0, stream>>>((const float4*)nvec, (float4*)out,
                                           out_size / 4);
}

// Round 2
// 266.674 us; speedup vs baseline: 1.1031x; 1.1031x over previous
//
#include <hip/hip_runtime.h>

#define N_POS 4096
#define NJ 4094     // N-2 valid sign-change positions
#define RPB 32      // rows per count-block

// ---------------------------------------------------------------------------
// Kernel 1: count peaks/valleys of the second difference.
// Grid: (4 position-chunks of 1024, rows/RPB), block 256.
// Each thread owns 4 consecutive positions; loads float4 + overlapping float2
// (no shfl, no divergent halo); unroll-4 over rows for MLP; one packed
// atomicAdd per position (peak low16 | valley high16).
// ---------------------------------------------------------------------------
__global__ __launch_bounds__(256) void count_kernel(
    const float* __restrict__ x,
    unsigned int* __restrict__ cnt)
{
    const int tid = threadIdx.x;
    const int j0  = blockIdx.x * 1024 + tid * 4;
    const size_t row0 = (size_t)blockIdx.y * RPB;

    unsigned int pk0 = 0, pk1 = 0, pk2 = 0, pk3 = 0;
    unsigned int vl0 = 0, vl1 = 0, vl2 = 0, vl3 = 0;

    const float* base = x + row0 * N_POS + j0;
    const bool tail = (j0 + 4 >= N_POS);   // only j0 == 4092

    #pragma unroll 4
    for (int r = 0; r < RPB; ++r) {
        const float* rowp = base + (size_t)r * N_POS;
        float4 a = *reinterpret_cast<const float4*>(rowp);
        float n0 = 0.f, n1 = 0.f;
        if (!tail) {
            float2 b = *reinterpret_cast<const float2*>(rowp + 4);
            n0 = b.x; n1 = b.y;
        }
        float s;
        s = (a.z - a.y) - (a.y - a.x);
        pk0 += (s < 0.f); vl0 += (s > 0.f);
        s = (a.w - a.z) - (a.z - a.y);
        pk1 += (s < 0.f); vl1 += (s > 0.f);
        s = (n0 - a.w) - (a.w - a.z);
        pk2 += (s < 0.f); vl2 += (s > 0.f);
        s = (n1 - n0) - (n0 - a.w);
        pk3 += (s < 0.f); vl3 += (s > 0.f);
    }

    if (j0 + 0 < NJ) atomicAdd(&cnt[j0 + 0], pk0 | (vl0 << 16));
    if (j0 + 1 < NJ) atomicAdd(&cnt[j0 + 1], pk1 | (vl1 << 16));
    if (j0 + 2 < NJ) atomicAdd(&cnt[j0 + 2], pk2 | (vl2 << 16));
    if (j0 + 3 < NJ) atomicAdd(&cnt[j0 + 3], pk3 | (vl3 << 16));
}

// ---------------------------------------------------------------------------
// Kernel 2 (fused vec + norm): single block, 1024 threads.
// Stage counts + Gaussian weight tables in LDS, compute vec (FMAs only),
// block-reduce min/max, write normalized vec.
// Gaussian truncated at radius ceil(8w)+1 (terms < e^-64, negligible vs the
// 2e-2 absmax threshold on a [0,1]-normalized output).
// ---------------------------------------------------------------------------
__global__ __launch_bounds__(1024) void vecnorm_kernel(
    const unsigned int* __restrict__ cnt,
    const float* __restrict__ log_pw,
    const float* __restrict__ log_vw,
    float* __restrict__ nvec)
{
    __shared__ float s_pk[NJ];
    __shared__ float s_vl[NJ];
    __shared__ float s_gp[257];   // weights for dist in [-128, 128]
    __shared__ float s_gv[257];
    __shared__ float smin[16], smax[16];

    const int tid = threadIdx.x;
    const float wp = __expf(log_pw[0]);
    const float wv = __expf(log_vw[0]);
    const float ip2 = 1.f / (wp * wp);
    const float iv2 = 1.f / (wv * wv);
    const int Rp = min(128, (int)ceilf(wp * 8.f) + 1);
    const int Rv = min(128, (int)ceilf(wv * 8.f) + 1);

    for (int j = tid; j < NJ; j += 1024) {
        unsigned int c = cnt[j];
        s_pk[j] = (float)(c & 0xFFFFu);
        s_vl[j] = (float)(c >> 16);
    }
    for (int d = tid; d < 257; d += 1024) {
        float dd = (float)(d - 128);
        s_gp[d] = __expf(-dd * dd * ip2);
        s_gv[d] = __expf(-dd * dd * iv2);
    }
    __syncthreads();

    float v[4];
    float lmin = 1e30f, lmax = -1e30f;
    #pragma unroll
    for (int k = 0; k < 4; ++k) {
        const int p = tid + k * 1024;
        float sum = 0.f;
        {   // peaks: centers c = j+1 in [1, NJ]
            int clo = max(1, p - Rp), chi = min(NJ, p + Rp);
            for (int c = clo; c <= chi; ++c)
                sum += s_pk[c - 1] * s_gp[p - c + 128];
        }
        {   // valleys
            int clo = max(1, p - Rv), chi = min(NJ, p + Rv);
            for (int c = clo; c <= chi; ++c)
                sum += s_vl[c - 1] * s_gv[p - c + 128];
        }
        v[k] = sum;
        lmin = fminf(lmin, sum);
        lmax = fmaxf(lmax, sum);
    }

    for (int off = 32; off; off >>= 1) {
        lmin = fminf(lmin, __shfl_down(lmin, off));
        lmax = fmaxf(lmax, __shfl_down(lmax, off));
    }
    const int wave = tid >> 6;
    if ((tid & 63) == 0) { smin[wave] = lmin; smax[wave] = lmax; }
    __syncthreads();
    if (tid == 0) {
        float mn = smin[0], mx = smax[0];
        #pragma unroll
        for (int i = 1; i < 16; ++i) {
            mn = fminf(mn, smin[i]);
            mx = fmaxf(mx, smax[i]);
        }
        smin[0] = mn; smax[0] = mx;
    }
    __syncthreads();
    const float vmin = smin[0];
    const float inv  = 1.f / (smax[0] - vmin + 1e-6f);
    #pragma unroll
    for (int k = 0; k < 4; ++k)
        nvec[tid + k * 1024] = (v[k] - vmin) * inv;
}

// ---------------------------------------------------------------------------
// Kernel 3: broadcast nvec (16 KiB, L1-resident) to all B*C rows.
// ---------------------------------------------------------------------------
__global__ __launch_bounds__(256) void bcast_kernel(
    const float4* __restrict__ nvec4, float4* __restrict__ out4, int total4)
{
    int idx    = blockIdx.x * blockDim.x + threadIdx.x;
    int stride = gridDim.x * blockDim.x;
    for (int i = idx; i < total4; i += stride)
        out4[i] = nvec4[i & 1023];   // N/4 = 1024 (power of two)
}

extern "C" void kernel_launch(void* const* d_in, const int* in_sizes, int n_in,
                              void* d_out, int out_size, void* d_ws, size_t ws_size,
                              hipStream_t stream) {
    const float* x   = (const float*)d_in[0];
    const float* lpw = (const float*)d_in[1];
    const float* lvw = (const float*)d_in[2];
    float* out = (float*)d_out;

    unsigned int* cnt = (unsigned int*)d_ws;
    float* nvec = (float*)(cnt + 4096);

    const int rows = in_sizes[0] / N_POS;   // 8192

    // zero the packed counters (ws is poisoned 0xAA before every timed launch)
    hipMemsetAsync(cnt, 0, 4096 * sizeof(unsigned int), stream);

    dim3 g1(4, rows / RPB);
    count_kernel<<<g1, 256, 0, stream>>>(x, cnt);
    vecnorm_kernel<<<1, 1024, 0, stream>>>(cnt, lpw, lvw, nvec);
    bcast_kernel<<<2048, 256, 0, stream>>>((const float4*)nvec, (float4*)out,
                                           out_size / 4);
}

// Round 3
// 259.879 us; speedup vs baseline: 1.1319x; 1.0261x over previous
//
#include <hip/hip_runtime.h>

#define N_POS 4096
#define NJ 4094     // N-2 valid sign-change positions
#define RPB 16      // rows per count-block

// ---------------------------------------------------------------------------
// Kernel 1: count peaks/valleys of the second difference.
// Grid: (4 position-chunks of 1024, rows/RPB = 512), block 256 → 2048 blocks,
// 8 waves/CU. Each thread owns 4 consecutive positions; loads float4 +
// overlapping float2 (halo without shfl); fully unrolled 16-row loop for MLP;
// one packed atomicAdd per position (peak low16 | valley high16).
// ---------------------------------------------------------------------------
__global__ __launch_bounds__(256) void count_kernel(
    const float* __restrict__ x,
    unsigned int* __restrict__ cnt)
{
    const int tid = threadIdx.x;
    const int j0  = blockIdx.x * 1024 + tid * 4;
    const size_t row0 = (size_t)blockIdx.y * RPB;

    unsigned int pk0 = 0, pk1 = 0, pk2 = 0, pk3 = 0;
    unsigned int vl0 = 0, vl1 = 0, vl2 = 0, vl3 = 0;

    const float* base = x + row0 * N_POS + j0;
    const bool tail = (j0 + 4 >= N_POS);   // only j0 == 4092

    #pragma unroll
    for (int r = 0; r < RPB; ++r) {
        const float* rowp = base + (size_t)r * N_POS;
        float4 a = *reinterpret_cast<const float4*>(rowp);
        float n0 = 0.f, n1 = 0.f;
        if (!tail) {
            float2 b = *reinterpret_cast<const float2*>(rowp + 4);
            n0 = b.x; n1 = b.y;
        }
        float s;
        s = (a.z - a.y) - (a.y - a.x);
        pk0 += (s < 0.f); vl0 += (s > 0.f);
        s = (a.w - a.z) - (a.z - a.y);
        pk1 += (s < 0.f); vl1 += (s > 0.f);
        s = (n0 - a.w) - (a.w - a.z);
        pk2 += (s < 0.f); vl2 += (s > 0.f);
        s = (n1 - n0) - (n0 - a.w);
        pk3 += (s < 0.f); vl3 += (s > 0.f);
    }

    if (j0 + 0 < NJ) atomicAdd(&cnt[j0 + 0], pk0 | (vl0 << 16));
    if (j0 + 1 < NJ) atomicAdd(&cnt[j0 + 1], pk1 | (vl1 << 16));
    if (j0 + 2 < NJ) atomicAdd(&cnt[j0 + 2], pk2 | (vl2 << 16));
    if (j0 + 3 < NJ) atomicAdd(&cnt[j0 + 3], pk3 | (vl3 << 16));
}

// ---------------------------------------------------------------------------
// Kernel 2: vec + global min/max. 16 blocks x 256 threads, one position per
// thread. Counts staged in LDS with +/-130 halo; Gaussian weight tables in
// LDS (truncated at radius ceil(8w)+1 <= 128; dropped terms < e^-64,
// negligible vs the 2e-2 absmax threshold on a [0,1]-normalized output).
// Min/max via monotonic-uint atomicMax (vec >= 0): mm[0] holds
// max(0x7FFFFFFF - bits(v)) -> decodes to min; mm[1] holds max(bits(v)).
// Both init to 0 by the same memset that zeroes cnt.
// ---------------------------------------------------------------------------
__global__ __launch_bounds__(256) void vec_kernel(
    const unsigned int* __restrict__ cnt,
    const float* __restrict__ log_pw,
    const float* __restrict__ log_vw,
    float* __restrict__ vec,
    unsigned int* __restrict__ mm)
{
    __shared__ float s_pk[520];
    __shared__ float s_vl[520];
    __shared__ float s_gp[257];   // weights for dist in [-128, 128]
    __shared__ float s_gv[257];
    __shared__ float smn[4], smx[4];

    const int tid = threadIdx.x;
    const int jb  = blockIdx.x * 256 - 130;

    const float wp = __expf(log_pw[0]);
    const float wv = __expf(log_vw[0]);
    const float ip2 = 1.f / (wp * wp);
    const float iv2 = 1.f / (wv * wv);
    const int Rp = min(128, (int)ceilf(wp * 8.f) + 1);
    const int Rv = min(128, (int)ceilf(wv * 8.f) + 1);

    for (int i = tid; i < 520; i += 256) {
        int j = jb + i;
        unsigned int c = (j >= 0 && j < NJ) ? cnt[j] : 0u;
        s_pk[i] = (float)(c & 0xFFFFu);
        s_vl[i] = (float)(c >> 16);
    }
    for (int i = tid; i < 257; i += 256) {
        float dd = (float)(i - 128);
        s_gp[i] = __expf(-dd * dd * ip2);
        s_gv[i] = __expf(-dd * dd * iv2);
    }
    __syncthreads();

    const int p = blockIdx.x * 256 + tid;
    float sum = 0.f;
    {   // peaks: centers c = j+1 in [1, NJ]
        int clo = max(1, p - Rp), chi = min(NJ, p + Rp);
        for (int c = clo; c <= chi; ++c)
            sum += s_pk[c - 1 - jb] * s_gp[p - c + 128];
    }
    {   // valleys
        int clo = max(1, p - Rv), chi = min(NJ, p + Rv);
        for (int c = clo; c <= chi; ++c)
            sum += s_vl[c - 1 - jb] * s_gv[p - c + 128];
    }
    vec[p] = sum;

    float mn = sum, mx = sum;
    for (int off = 32; off; off >>= 1) {
        mn = fminf(mn, __shfl_down(mn, off));
        mx = fmaxf(mx, __shfl_down(mx, off));
    }
    if ((tid & 63) == 0) { smn[tid >> 6] = mn; smx[tid >> 6] = mx; }
    __syncthreads();
    if (tid == 0) {
        mn = fminf(fminf(smn[0], smn[1]), fminf(smn[2], smn[3]));
        mx = fmaxf(fmaxf(smx[0], smx[1]), fmaxf(smx[2], smx[3]));
        atomicMax(&mm[0], 0x7FFFFFFFu - __float_as_uint(mn));  // min key
        atomicMax(&mm[1], __float_as_uint(mx));                // max key
    }
}

// ---------------------------------------------------------------------------
// Kernel 3: broadcast + normalize. vec (16 KiB) is L1/L2-resident; write-
// bound at ~134 MB. Normalization fused (4 FMAs per float4 store, free).
// ---------------------------------------------------------------------------
__global__ __launch_bounds__(256) void bcast_kernel(
    const float4* __restrict__ vec4,
    const unsigned int* __restrict__ mm,
    float4* __restrict__ out4, int total4)
{
    const float mn  = __uint_as_float(0x7FFFFFFFu - mm[0]);
    const float mx  = __uint_as_float(mm[1]);
    const float inv = 1.f / (mx - mn + 1e-6f);

    int idx    = blockIdx.x * blockDim.x + threadIdx.x;
    int stride = gridDim.x * blockDim.x;
    for (int i = idx; i < total4; i += stride) {
        float4 v = vec4[i & 1023];   // N/4 = 1024 (power of two)
        float4 o;
        o.x = (v.x - mn) * inv;
        o.y = (v.y - mn) * inv;
        o.z = (v.z - mn) * inv;
        o.w = (v.w - mn) * inv;
        out4[i] = o;
    }
}

extern "C" void kernel_launch(void* const* d_in, const int* in_sizes, int n_in,
                              void* d_out, int out_size, void* d_ws, size_t ws_size,
                              hipStream_t stream) {
    const float* x   = (const float*)d_in[0];
    const float* lpw = (const float*)d_in[1];
    const float* lvw = (const float*)d_in[2];
    float* out = (float*)d_out;

    unsigned int* cnt = (unsigned int*)d_ws;      // [0..4095] packed counts
    unsigned int* mm  = cnt + 4096;               // [4096..4097] min/max keys
    float* vec = (float*)d_ws + 4352;             // 16-byte aligned

    const int rows = in_sizes[0] / N_POS;         // 8192

    // one memset zeroes counters AND the two minmax keys
    hipMemsetAsync(cnt, 0, (4096 + 2) * sizeof(unsigned int), stream);

    dim3 g1(4, rows / RPB);
    count_kernel<<<g1, 256, 0, stream>>>(x, cnt);
    vec_kernel<<<16, 256, 0, stream>>>(cnt, lpw, lvw, vec, mm);
    bcast_kernel<<<2048, 256, 0, stream>>>((const float4*)vec, mm,
                                           (float4*)out, out_size / 4);
}

// Round 6
// 256.494 us; speedup vs baseline: 1.1469x; 1.0132x over previous
//
#include <hip/hip_runtime.h>

#define N_POS 4096
#define NJ 4094     // N-2 valid sign-change positions
#define RPB 16      // rows per count-block

typedef float f32x4 __attribute__((ext_vector_type(4)));  // nt-store-compatible

// ---------------------------------------------------------------------------
// Kernel 1: count peaks/valleys of the second difference.
// Grid: (4 position-chunks of 1024, rows/RPB = 512) = 2048 blocks, block 256.
// Each thread owns 4 consecutive positions. Loads are REGISTER-STAGED in two
// half-batches of 8 rows (8 x {float4 + float2} issued back-to-back before
// any compute) so each wave keeps ~12 KB in flight -> BW-bound, not
// latency-bound. Halo handled branch-free: the single tail thread
// (j0 == 4092) clamps its halo pointer in-bounds; the values only feed
// positions >= NJ whose atomics are guarded off anyway.
// One packed atomicAdd per position (peak low16 | valley high16).
// ---------------------------------------------------------------------------
__global__ __launch_bounds__(256) void count_kernel(
    const float* __restrict__ x,
    unsigned int* __restrict__ cnt)
{
    const int tid = threadIdx.x;
    const int j0  = blockIdx.x * 1024 + tid * 4;
    const size_t row0 = (size_t)blockIdx.y * RPB;

    const float* base = x + row0 * N_POS + j0;
    const bool tail = (j0 + 4 >= N_POS);     // only j0 == 4092
    const int halo_off = tail ? -2 : 4;      // tail reads in-bounds garbage

    unsigned int pk0 = 0, pk1 = 0, pk2 = 0, pk3 = 0;
    unsigned int vl0 = 0, vl1 = 0, vl2 = 0, vl3 = 0;

    #pragma unroll
    for (int h = 0; h < RPB / 8; ++h) {
        float4 A[8];
        float2 B[8];
        const float* hb = base + (size_t)(h * 8) * N_POS;
        #pragma unroll
        for (int r = 0; r < 8; ++r) {
            const float* rowp = hb + (size_t)r * N_POS;
            A[r] = *reinterpret_cast<const float4*>(rowp);
            B[r] = *reinterpret_cast<const float2*>(rowp + halo_off);
        }
        #pragma unroll
        for (int r = 0; r < 8; ++r) {
            const float4 a = A[r];
            const float n0 = B[r].x, n1 = B[r].y;
            float s;
            s = (a.z - a.y) - (a.y - a.x);
            pk0 += (s < 0.f); vl0 += (s > 0.f);
            s = (a.w - a.z) - (a.z - a.y);
            pk1 += (s < 0.f); vl1 += (s > 0.f);
            s = (n0 - a.w) - (a.w - a.z);
            pk2 += (s < 0.f); vl2 += (s > 0.f);
            s = (n1 - n0) - (n0 - a.w);
            pk3 += (s < 0.f); vl3 += (s > 0.f);
        }
    }

    if (j0 + 0 < NJ) atomicAdd(&cnt[j0 + 0], pk0 | (vl0 << 16));
    if (j0 + 1 < NJ) atomicAdd(&cnt[j0 + 1], pk1 | (vl1 << 16));
    if (j0 + 2 < NJ) atomicAdd(&cnt[j0 + 2], pk2 | (vl2 << 16));
    if (j0 + 3 < NJ) atomicAdd(&cnt[j0 + 3], pk3 | (vl3 << 16));
}

// ---------------------------------------------------------------------------
// Kernel 2: vec + global min/max. 16 blocks x 256 threads, one position per
// thread. Counts staged in LDS with +/-130 halo; Gaussian weight tables in
// LDS (truncated at radius ceil(8w)+1 <= 128; dropped terms < e^-64,
// negligible vs the 2e-2 absmax threshold on a [0,1]-normalized output).
// Min/max via monotonic-uint atomicMax (vec >= 0): mm[0] holds
// max(0x7FFFFFFF - bits(v)) -> decodes to min; mm[1] holds max(bits(v)).
// Both init to 0 by the same memset that zeroes cnt.
// ---------------------------------------------------------------------------
__global__ __launch_bounds__(256) void vec_kernel(
    const unsigned int* __restrict__ cnt,
    const float* __restrict__ log_pw,
    const float* __restrict__ log_vw,
    float* __restrict__ vec,
    unsigned int* __restrict__ mm)
{
    __shared__ float s_pk[520];
    __shared__ float s_vl[520];
    __shared__ float s_gp[257];   // weights for dist in [-128, 128]
    __shared__ float s_gv[257];
    __shared__ float smn[4], smx[4];

    const int tid = threadIdx.x;
    const int jb  = blockIdx.x * 256 - 130;

    const float wp = __expf(log_pw[0]);
    const float wv = __expf(log_vw[0]);
    const float ip2 = 1.f / (wp * wp);
    const float iv2 = 1.f / (wv * wv);
    const int Rp = min(128, (int)ceilf(wp * 8.f) + 1);
    const int Rv = min(128, (int)ceilf(wv * 8.f) + 1);

    for (int i = tid; i < 520; i += 256) {
        int j = jb + i;
        unsigned int c = (j >= 0 && j < NJ) ? cnt[j] : 0u;
        s_pk[i] = (float)(c & 0xFFFFu);
        s_vl[i] = (float)(c >> 16);
    }
    for (int i = tid; i < 257; i += 256) {
        float dd = (float)(i - 128);
        s_gp[i] = __expf(-dd * dd * ip2);
        s_gv[i] = __expf(-dd * dd * iv2);
    }
    __syncthreads();

    const int p = blockIdx.x * 256 + tid;
    float sum = 0.f;
    {   // peaks: centers c = j+1 in [1, NJ]
        int clo = max(1, p - Rp), chi = min(NJ, p + Rp);
        for (int c = clo; c <= chi; ++c)
            sum += s_pk[c - 1 - jb] * s_gp[p - c + 128];
    }
    {   // valleys
        int clo = max(1, p - Rv), chi = min(NJ, p + Rv);
        for (int c = clo; c <= chi; ++c)
            sum += s_vl[c - 1 - jb] * s_gv[p - c + 128];
    }
    vec[p] = sum;

    float mn = sum, mx = sum;
    for (int off = 32; off; off >>= 1) {
        mn = fminf(mn, __shfl_down(mn, off));
        mx = fmaxf(mx, __shfl_down(mx, off));
    }
    if ((tid & 63) == 0) { smn[tid >> 6] = mn; smx[tid >> 6] = mx; }
    __syncthreads();
    if (tid == 0) {
        mn = fminf(fminf(smn[0], smn[1]), fminf(smn[2], smn[3]));
        mx = fmaxf(fmaxf(smx[0], smx[1]), fmaxf(smx[2], smx[3]));
        atomicMax(&mm[0], 0x7FFFFFFFu - __float_as_uint(mn));  // min key
        atomicMax(&mm[1], __float_as_uint(mx));                // max key
    }
}

// ---------------------------------------------------------------------------
// Kernel 3: broadcast + normalize. vec (16 KiB) is L1/L2-resident; write-
// bound at ~134 MB. Nontemporal stores (via native ext_vector_type) skip L2
// write-allocate. Normalization fused (4 FMAs per float4 store, free
// against the write BW).
// ---------------------------------------------------------------------------
__global__ __launch_bounds__(256) void bcast_kernel(
    const float4* __restrict__ vec4,
    const unsigned int* __restrict__ mm,
    f32x4* __restrict__ out4, int total4)
{
    const float mn  = __uint_as_float(0x7FFFFFFFu - mm[0]);
    const float mx  = __uint_as_float(mm[1]);
    const float inv = 1.f / (mx - mn + 1e-6f);

    int idx    = blockIdx.x * blockDim.x + threadIdx.x;
    int stride = gridDim.x * blockDim.x;
    for (int i = idx; i < total4; i += stride) {
        float4 v = vec4[i & 1023];   // N/4 = 1024 (power of two)
        f32x4 o;
        o.x = (v.x - mn) * inv;
        o.y = (v.y - mn) * inv;
        o.z = (v.z - mn) * inv;
        o.w = (v.w - mn) * inv;
        __builtin_nontemporal_store(o, &out4[i]);
    }
}

extern "C" void kernel_launch(void* const* d_in, const int* in_sizes, int n_in,
                              void* d_out, int out_size, void* d_ws, size_t ws_size,
                              hipStream_t stream) {
    const float* x   = (const float*)d_in[0];
    const float* lpw = (const float*)d_in[1];
    const float* lvw = (const float*)d_in[2];

    unsigned int* cnt = (unsigned int*)d_ws;      // [0..4095] packed counts
    unsigned int* mm  = cnt + 4096;               // [4096..4097] min/max keys
    float* vec = (float*)d_ws + 4352;             // 16-byte aligned

    const int rows = in_sizes[0] / N_POS;         // 8192

    // one memset zeroes counters AND the two minmax keys
    (void)hipMemsetAsync(cnt, 0, (4096 + 2) * sizeof(unsigned int), stream);

    dim3 g1(4, rows / RPB);
    count_kernel<<<g1, 256, 0, stream>>>(x, cnt);
    vec_kernel<<<16, 256, 0, stream>>>(cnt, lpw, lvw, vec, mm);
    bcast_kernel<<<2048, 256, 0, stream>>>((const float4*)vec, mm,
                                           (f32x4*)d_out, out_size / 4);
}